// Round 4
// baseline (11964.788 us; speedup 1.0000x reference)
//
#include <hip/hip_runtime.h>
#include <cstdint>
#include <cstddef>

// tanh-RNN (SlimeMoldEncoder): S=1024, B=32, D=1024.
//   h_t = tanh(src[t]@W_in + h_{t-1}@W_rec + b_h);  out[t] = h_t@W_out + b_o
// R4: persistent recurrence with DATA-EMBEDDED validity tags: H stored as f32
// with mantissa-LSB=1 epoch tag; consumers poll the data itself (1 IF$ RTT,
// no flags, no producer-side drain). Double-buffered K-split partials
// (1 barrier/step). GEMMs take f32 A directly (convert during LDS staging).

#define S_LEN 1024
#define B_SZ  32
#define D_MOD 1024
#define M_TOT (S_LEN * B_SZ)  // 32768
#define NBLK  32              // rnn blocks; each owns 32 columns

typedef __attribute__((ext_vector_type(8))) short    short8;   // 8 bf16
typedef __attribute__((ext_vector_type(4))) float    floatx4;  // MFMA acc
typedef unsigned long long u64;

#define TAGM 0x0000000100000001ULL  // LSB of both f32 words in a u64

__device__ __forceinline__ unsigned short f2bf(float f) {
  unsigned int u = __float_as_uint(f);
  unsigned int lsb = (u >> 16) & 1u;
  u += 0x7fffu + lsb;  // RNE
  return (unsigned short)(u >> 16);
}

__device__ __forceinline__ float tanh_fast(float x) {
  float xc = fminf(fmaxf(x, -9.f), 9.f);
  float e  = __expf(2.f * xc);
  return 1.f - 2.f / (e + 1.f);
}

// ---- W [K][N] f32 -> Wt [N][K] bf16 ----
__global__ __launch_bounds__(256) void transpose_w_kernel(
    const float* __restrict__ in, unsigned short* __restrict__ out) {
  __shared__ float tile[32][33];
  const int tx = threadIdx.x & 31;
  const int ty = threadIdx.x >> 5;
  const int kb = blockIdx.x * 32;
  const int nb = blockIdx.y * 32;
#pragma unroll
  for (int r = 0; r < 32; r += 8)
    tile[ty + r][tx] = in[(size_t)(kb + ty + r) * D_MOD + nb + tx];
  __syncthreads();
#pragma unroll
  for (int r = 0; r < 32; r += 8)
    out[(size_t)(nb + ty + r) * D_MOD + kb + tx] = f2bf(tile[tx][ty + r]);
}

// ---- big GEMM: C[M,N] f32 = A[M,K]f32(->bf16) @ Bt[N,K]bf16^T + bias ----
#define BM 128
#define BN 128
#define BK 32

__global__ __launch_bounds__(256) void gemm_bias_kernel(
    const float* __restrict__ A32,          // [M,K] f32 (low-bit tags ok)
    const unsigned short* __restrict__ Bt,  // [N,K] bf16
    const float* __restrict__ bias,         // [N]
    float* __restrict__ C,                  // [M,N]
    int M, int N, int K) {
  __shared__ unsigned short Asl[BM * BK];
  __shared__ unsigned short Bsl[BN * BK];
  const int tid  = threadIdx.x;
  const int lane = tid & 63;
  const int wave = tid >> 6;
  const int wm = wave >> 1, wn = wave & 1;
  const int m0 = blockIdx.y * BM;
  const int n0 = blockIdx.x * BN;

  floatx4 acc[4][4] = {};
  const int arow = tid >> 1;            // 0..127
  const int akq  = (tid & 1) * 16;      // 0 or 16
  const int r0   = tid >> 2;            // 0..63 (B staging)
  const int sl0  = (tid & 3) * 8;

  for (int ko = 0; ko < K; ko += BK) {
    // stage A: f32 -> bf16 during staging (4x float4 per thread)
#pragma unroll
    for (int q = 0; q < 4; ++q) {
      float4 v = *reinterpret_cast<const float4*>(
          &A32[(size_t)(m0 + arow) * K + ko + akq + q * 4]);
      ushort4 o;
      o.x = f2bf(v.x); o.y = f2bf(v.y); o.z = f2bf(v.z); o.w = f2bf(v.w);
      *reinterpret_cast<ushort4*>(&Asl[arow * BK + akq + q * 4]) = o;
    }
    *reinterpret_cast<short8*>(&Bsl[(r0)      * BK + sl0]) =
        *reinterpret_cast<const short8*>(&Bt[(size_t)(n0 + r0)      * K + ko + sl0]);
    *reinterpret_cast<short8*>(&Bsl[(r0 + 64) * BK + sl0]) =
        *reinterpret_cast<const short8*>(&Bt[(size_t)(n0 + r0 + 64) * K + ko + sl0]);
    __syncthreads();

    const int kr = (lane >> 4) * 8;
    short8 af[4], bf[4];
#pragma unroll
    for (int i = 0; i < 4; ++i)
      af[i] = *reinterpret_cast<const short8*>(&Asl[(wm * 64 + i * 16 + (lane & 15)) * BK + kr]);
#pragma unroll
    for (int j = 0; j < 4; ++j)
      bf[j] = *reinterpret_cast<const short8*>(&Bsl[(wn * 64 + j * 16 + (lane & 15)) * BK + kr]);
#pragma unroll
    for (int i = 0; i < 4; ++i)
#pragma unroll
      for (int j = 0; j < 4; ++j)
        acc[i][j] = __builtin_amdgcn_mfma_f32_16x16x32_bf16(af[i], bf[j], acc[i][j], 0, 0, 0);
    __syncthreads();
  }

  const int cl = lane & 15, rq = lane >> 4;
#pragma unroll
  for (int i = 0; i < 4; ++i) {
#pragma unroll
    for (int j = 0; j < 4; ++j) {
      const int n = n0 + wn * 64 + j * 16 + cl;
      const float bs = bias[n];
#pragma unroll
      for (int r = 0; r < 4; ++r) {
        const int m = m0 + wm * 64 + i * 16 + rq * 4 + r;
        C[(size_t)m * N + n] = acc[i][j][r] + bs;
      }
    }
  }
}

// ---- persistent recurrence: 32 blocks x 256 threads (4 waves, K-split) ----
// Block b owns output cols [32b, 32b+32). Wave w handles K in [256w, 256w+256).
// H stored f32 with LSB=1 tag; consumers poll data words directly (SYSTEM
// scope relaxed = sc0 sc1 cache-bypass -> IF$; no L2 maintenance ops).
__global__ __launch_bounds__(256, 1) void rnn_kernel(
    const unsigned short* __restrict__ Wrt,  // [N][K] bf16
    const float* __restrict__ Xpre,          // [S][32][1024] f32
    float* __restrict__ Hext) {              // [(S+1)][32][1024] f32 tagged
  __shared__ unsigned short wlds[NBLK * 1024];  // 64 KB W-slice fragments
  __shared__ float part[2][4][32][32];          // 32 KB double-buffered partials
  const int tid  = threadIdx.x;
  const int lane = tid & 63;
  const int w    = tid >> 6;   // wave id = K-quarter
  const int cl   = lane & 15;
  const int rq   = lane >> 4;
  const int n0   = blockIdx.x * 32;

  // stage W fragments for this wave's K-quarter (one-time)
#pragma unroll
  for (int g = 0; g < 8; ++g) {
    const int ga = w * 8 + g;
#pragma unroll
    for (int j = 0; j < 2; ++j) {
      const int n = n0 + j * 16 + cl;
      const int k = ga * 32 + rq * 8;
      *reinterpret_cast<short8*>(&wlds[(size_t)((ga * 2 + j) * 64 + lane) * 8]) =
          *reinterpret_cast<const short8*>(&Wrt[(size_t)n * D_MOD + k]);
    }
  }
  __syncthreads();

  // reduce-thread mapping: thread -> (row rr, col group c4)
  const int rr = tid >> 3;         // 0..31
  const int c4 = (tid & 7) * 4;    // 0,4,..,28
  float4 xv = *reinterpret_cast<const float4*>(&Xpre[(size_t)rr * D_MOD + n0 + c4]);

  const int kbase = w * 256 + rq * 8;  // this lane's k start within H row

  for (int t = 0; t < S_LEN; ++t) {
    const float* Hp = Hext + (size_t)t * B_SZ * D_MOD;

    // ---- poll-on-data: load 64 u64 (2 rows x 256 k as f32), all tagged ----
    u64 d[8][2][4];
#pragma unroll
    for (int g = 0; g < 8; ++g)
#pragma unroll
      for (int r = 0; r < 2; ++r)
#pragma unroll
        for (int q = 0; q < 4; ++q)
          d[g][r][q] = __hip_atomic_load(
              (const u64*)&Hp[(size_t)(r * 16 + cl) * D_MOD + kbase + g * 32 + q * 2],
              __ATOMIC_RELAXED, __HIP_MEMORY_SCOPE_SYSTEM);
    while (true) {
      bool ok = true;
#pragma unroll
      for (int g = 0; g < 8; ++g)
#pragma unroll
        for (int r = 0; r < 2; ++r)
#pragma unroll
          for (int q = 0; q < 4; ++q)
            if ((d[g][r][q] & TAGM) != TAGM) {
              d[g][r][q] = __hip_atomic_load(
                  (const u64*)&Hp[(size_t)(r * 16 + cl) * D_MOD + kbase + g * 32 + q * 2],
                  __ATOMIC_RELAXED, __HIP_MEMORY_SCOPE_SYSTEM);
              ok = false;
            }
      if (ok) break;
    }

    // ---- convert to bf16 frags + MFMA (K-quarter) ----
    floatx4 acc[2][2] = {};
#pragma unroll
    for (int g = 0; g < 8; ++g) {
      const int ga = w * 8 + g;
      short8 a0, a1;
#pragma unroll
      for (int q = 0; q < 4; ++q) {
        a0[q * 2]     = (short)f2bf(__uint_as_float((unsigned)d[g][0][q]));
        a0[q * 2 + 1] = (short)f2bf(__uint_as_float((unsigned)(d[g][0][q] >> 32)));
        a1[q * 2]     = (short)f2bf(__uint_as_float((unsigned)d[g][1][q]));
        a1[q * 2 + 1] = (short)f2bf(__uint_as_float((unsigned)(d[g][1][q] >> 32)));
      }
      short8 b0 = *reinterpret_cast<const short8*>(&wlds[(size_t)((ga * 2 + 0) * 64 + lane) * 8]);
      short8 b1 = *reinterpret_cast<const short8*>(&wlds[(size_t)((ga * 2 + 1) * 64 + lane) * 8]);
      acc[0][0] = __builtin_amdgcn_mfma_f32_16x16x32_bf16(a0, b0, acc[0][0], 0, 0, 0);
      acc[0][1] = __builtin_amdgcn_mfma_f32_16x16x32_bf16(a1, b0, acc[0][1], 0, 0, 0);
      acc[1][0] = __builtin_amdgcn_mfma_f32_16x16x32_bf16(a0, b1, acc[1][0], 0, 0, 0);
      acc[1][1] = __builtin_amdgcn_mfma_f32_16x16x32_bf16(a1, b1, acc[1][1], 0, 0, 0);
    }

    // ---- K-partials to LDS (double-buffered), one barrier ----
    const int buf = t & 1;
#pragma unroll
    for (int j = 0; j < 2; ++j)
#pragma unroll
      for (int h = 0; h < 2; ++h)
#pragma unroll
        for (int r = 0; r < 4; ++r)
          part[buf][w][h * 16 + rq * 4 + r][j * 16 + cl] = acc[j][h][r];
    __syncthreads();

    // ---- reduce + tanh + tagged f32 store (2x 8B system-scope) ----
    const float* pr = &part[buf][0][rr][c4];
    float4 s0 = *reinterpret_cast<const float4*>(pr);
    float4 s1 = *reinterpret_cast<const float4*>(pr + 1024);
    float4 s2 = *reinterpret_cast<const float4*>(pr + 2048);
    float4 s3 = *reinterpret_cast<const float4*>(pr + 3072);
    float vx = tanh_fast(s0.x + s1.x + s2.x + s3.x + xv.x);
    float vy = tanh_fast(s0.y + s1.y + s2.y + s3.y + xv.y);
    float vz = tanh_fast(s0.z + s1.z + s2.z + s3.z + xv.z);
    float vw = tanh_fast(s0.w + s1.w + s2.w + s3.w + xv.w);
    unsigned int t0 = __float_as_uint(vx) | 1u;
    unsigned int t1 = __float_as_uint(vy) | 1u;
    unsigned int t2 = __float_as_uint(vz) | 1u;
    unsigned int t3 = __float_as_uint(vw) | 1u;
    u64 lo = (u64)t0 | ((u64)t1 << 32);
    u64 hi = (u64)t2 | ((u64)t3 << 32);
    float* Hn = Hext + (size_t)(t + 1) * B_SZ * D_MOD;
    __hip_atomic_store((u64*)&Hn[(size_t)rr * D_MOD + n0 + c4],     lo,
                       __ATOMIC_RELAXED, __HIP_MEMORY_SCOPE_SYSTEM);
    __hip_atomic_store((u64*)&Hn[(size_t)rr * D_MOD + n0 + c4 + 2], hi,
                       __ATOMIC_RELAXED, __HIP_MEMORY_SCOPE_SYSTEM);

    // prefetch next step's Xpre (plain cached load)
    if (t + 1 < S_LEN)
      xv = *reinterpret_cast<const float4*>(
          &Xpre[(size_t)(t + 1) * B_SZ * D_MOD + rr * D_MOD + n0 + c4]);
  }
}

extern "C" void kernel_launch(void* const* d_in, const int* in_sizes, int n_in,
                              void* d_out, int out_size, void* d_ws, size_t ws_size,
                              hipStream_t stream) {
  const float* src   = (const float*)d_in[0];
  const float* W_in  = (const float*)d_in[1];
  const float* W_rec = (const float*)d_in[2];
  const float* W_out = (const float*)d_in[3];
  const float* b_h   = (const float*)d_in[4];
  const float* b_o   = (const float*)d_in[5];
  float* out = (float*)d_out;

  char* ws = (char*)d_ws;
  unsigned short* Wt_in  = (unsigned short*)ws; ws += (size_t)D_MOD * D_MOD * 2;
  unsigned short* Wt_rec = (unsigned short*)ws; ws += (size_t)D_MOD * D_MOD * 2;
  unsigned short* Wt_out = (unsigned short*)ws; ws += (size_t)D_MOD * D_MOD * 2;
  float*          Xpre   = (float*)ws;          ws += (size_t)M_TOT * D_MOD * 4;
  float*          Hext   = (float*)ws;          // [(S+1)][32][1024] f32 tagged

  dim3 tg(32, 32);
  transpose_w_kernel<<<tg, 256, 0, stream>>>(W_in,  Wt_in);
  transpose_w_kernel<<<tg, 256, 0, stream>>>(W_rec, Wt_rec);
  transpose_w_kernel<<<tg, 256, 0, stream>>>(W_out, Wt_out);
  // h0: bytes 0x01 -> f32 2.4e-38 (effectively 0) with LSB tag = 1 on every word
  hipMemsetAsync(Hext, 0x01, (size_t)B_SZ * D_MOD * 4, stream);

  dim3 g1(D_MOD / BN, M_TOT / BM);  // (8, 256)
  gemm_bias_kernel<<<g1, 256, 0, stream>>>(src, Wt_in, b_h, Xpre, M_TOT, D_MOD, D_MOD);

  rnn_kernel<<<NBLK, 256, 0, stream>>>(Wt_rec, Xpre, Hext);

  gemm_bias_kernel<<<g1, 256, 0, stream>>>(
      Hext + (size_t)B_SZ * D_MOD, Wt_out, b_o, out, M_TOT, D_MOD, D_MOD);
}